// Round 3
// baseline (1780.358 us; speedup 1.0000x reference)
//
#include <hip/hip_runtime.h>
#include <math.h>

// GCN forward: N=100000, IN_DIM=128, D=64, L=4, C=40, E=1.6M.
// Round 3: input GEMM as split-K (2 waves/node, w[64] each, LDS combine per
// 32-node round) -- round-2 post-mortem showed VGPR_Count=76 (<128): compiler
// refused to keep w[128] resident, and 2048 waves couldn't hide s_load latency.
// gemm_stats/out get launch_bounds(256,2) + 2x grid. agg gets 8-deep MLP.

#define LEAKY_SLOPE 0.2f
#define BN_EPS 1e-5f

// ---------------- CSR build ----------------

__global__ __launch_bounds__(256, 8)
void hist_kernel(const int* __restrict__ src, const int* __restrict__ dst,
                 int* __restrict__ cnt_src, int* __restrict__ cnt_dst, int E) {
  int i = blockIdx.x * blockDim.x + threadIdx.x;
  int stride = gridDim.x * blockDim.x;
  for (; i < E; i += stride) {
    atomicAdd(&cnt_src[src[i]], 1);
    atomicAdd(&cnt_dst[dst[i]], 1);
  }
}

__global__ __launch_bounds__(256, 8)
void norm_offsets_kernel(const int* __restrict__ cnt_src, const int* __restrict__ cnt_dst,
                         float* __restrict__ norm_src, float* __restrict__ norm_dst,
                         int* __restrict__ row_start, int* __restrict__ cursor,
                         int* __restrict__ g_cursor, int N) {
  int i = blockIdx.x * blockDim.x + threadIdx.x;
  int lane = threadIdx.x & 63;
  int cs = 0, cd = 0;
  if (i < N) { cs = cnt_src[i]; cd = cnt_dst[i]; }
  if (i < N) {
    norm_src[i] = rsqrtf(fmaxf((float)cs, 1.0f));
    norm_dst[i] = rsqrtf(fmaxf((float)cd, 1.0f));
  }
  int x = cd;
  #pragma unroll
  for (int off = 1; off < 64; off <<= 1) {
    int y = __shfl_up(x, off);
    if (lane >= off) x += y;
  }
  int excl = x - cd;
  int total = __shfl(x, 63);
  int base = 0;
  if (lane == 63) base = atomicAdd(g_cursor, total);
  base = __shfl(base, 63);
  if (i < N) {
    int rs = base + excl;
    row_start[i] = rs;
    cursor[i] = rs;
  }
}

__global__ __launch_bounds__(256, 8)
void fill_kernel(const int* __restrict__ src, const int* __restrict__ dst,
                 int* __restrict__ cursor, int* __restrict__ bucket, int E) {
  int i = blockIdx.x * blockDim.x + threadIdx.x;
  int stride = gridDim.x * blockDim.x;
  for (; i < E; i += stride) {
    int d = dst[i];
    int p = atomicAdd(&cursor[d], 1);
    bucket[p] = src[i];
  }
}

// ---------------- input GEMM: h = V @ W_in + b_in (128->64); hs = h*norm_src ----
// Split-K: wave (half,grp) holds w[64] for its K-half; 16 nodes per wave per
// round; partials combined through LDS. 32 nodes per block-round.
__global__ __launch_bounds__(256, 4)
void input_gemm_kernel(const float* __restrict__ V, const float* __restrict__ W_in,
                       const float* __restrict__ b_in, const float* __restrict__ norm_src,
                       float* __restrict__ h, float* __restrict__ hs, int N) {
  __shared__ __align__(16) float part[4][16][64];
  int tid = threadIdx.x;
  int lane = tid & 63;
  int wv = __builtin_amdgcn_readfirstlane(tid >> 6);  // 0..3
  int half = wv & 1, grp = wv >> 1;
  float w[64];
  #pragma unroll
  for (int k = 0; k < 64; k++) w[k] = W_in[(half * 64 + k) * 64 + lane];
  float bias = (half == 0) ? b_in[lane] : 0.f;

  for (int base = blockIdx.x * 32; base < N; base += gridDim.x * 32) {
    for (int i = 0; i < 16; i++) {
      int n = base + grp * 16 + i;
      float acc = bias;
      if (n < N) {
        const float* vrow = V + (size_t)n * 128 + half * 64;  // SGPR base -> s_load
        #pragma unroll
        for (int k = 0; k < 64; k++) acc += vrow[k] * w[k];
      }
      part[wv][i][lane] = acc;
    }
    __syncthreads();
    #pragma unroll
    for (int rep = 0; rep < 2; rep++) {
      int f4 = tid + rep * 256;        // 0..511 float4 slots (32 nodes x 16)
      int nl = f4 >> 4;                // node_local 0..31
      int c4 = (f4 & 15) * 4;
      int g2 = nl >> 4, il = nl & 15;
      int n = base + nl;
      if (n < N) {
        float4 a = *(const float4*)&part[g2 * 2 + 0][il][c4];
        float4 bq = *(const float4*)&part[g2 * 2 + 1][il][c4];
        float4 o;
        o.x = a.x + bq.x; o.y = a.y + bq.y; o.z = a.z + bq.z; o.w = a.w + bq.w;
        *(float4*)&h[(size_t)n * 64 + c4] = o;
        float nsc = norm_src[n];
        float4 s;
        s.x = o.x * nsc; s.y = o.y * nsc; s.z = o.z * nsc; s.w = o.w * nsc;
        *(float4*)&hs[(size_t)n * 64 + c4] = s;
      }
    }
    __syncthreads();
  }
}

// ---------------- aggregation: agg[n] = norm_dst[n] * sum_{e: dst=n} hs[src_e] ----
__global__ __launch_bounds__(256, 8)
void agg_kernel(const float* __restrict__ hs, const float* __restrict__ norm_dst,
                const int* __restrict__ row_start, const int* __restrict__ cnt_dst,
                const int* __restrict__ bucket, float* __restrict__ agg, int N) {
  int wid = __builtin_amdgcn_readfirstlane(blockIdx.x * 4 + (threadIdx.x >> 6));
  int lane = threadIdx.x & 63;
  if (wid >= N) return;
  int start = row_start[wid];
  int len = cnt_dst[wid];
  float nd = norm_dst[wid];
  const int* bkt = bucket + start;  // SGPR base -> s_load indices
  float a0=0.f,a1=0.f,a2=0.f,a3=0.f,a4=0.f,a5=0.f,a6=0.f,a7=0.f;
  for (int j = 0; j < len; j += 8) {
    // len is wave-uniform -> uniform predication, 8 loads in flight
    int s0=0,s1=0,s2=0,s3=0,s4=0,s5=0,s6=0,s7=0;
    if (j + 0 < len) s0 = bkt[j + 0];
    if (j + 1 < len) s1 = bkt[j + 1];
    if (j + 2 < len) s2 = bkt[j + 2];
    if (j + 3 < len) s3 = bkt[j + 3];
    if (j + 4 < len) s4 = bkt[j + 4];
    if (j + 5 < len) s5 = bkt[j + 5];
    if (j + 6 < len) s6 = bkt[j + 6];
    if (j + 7 < len) s7 = bkt[j + 7];
    if (j + 0 < len) a0 += hs[(size_t)s0 * 64 + lane];
    if (j + 1 < len) a1 += hs[(size_t)s1 * 64 + lane];
    if (j + 2 < len) a2 += hs[(size_t)s2 * 64 + lane];
    if (j + 3 < len) a3 += hs[(size_t)s3 * 64 + lane];
    if (j + 4 < len) a4 += hs[(size_t)s4 * 64 + lane];
    if (j + 5 < len) a5 += hs[(size_t)s5 * 64 + lane];
    if (j + 6 < len) a6 += hs[(size_t)s6 * 64 + lane];
    if (j + 7 < len) a7 += hs[(size_t)s7 * 64 + lane];
  }
  float acc = ((a0 + a1) + (a2 + a3)) + ((a4 + a5) + (a6 + a7));
  agg[(size_t)wid * 64 + lane] = acc * nd;
}

// ---------------- layer GEMM + BN stats: hc = agg @ W + b; stats += (sum,sumsq) ----
__global__ __launch_bounds__(256, 2)
void gemm_stats_kernel(const float* __restrict__ agg, const float* __restrict__ W,
                       const float* __restrict__ b, float* __restrict__ hc,
                       float* __restrict__ stats, int N) {
  int gw = (int)((blockIdx.x * blockDim.x + threadIdx.x) >> 6);
  int nw = (int)((gridDim.x * blockDim.x) >> 6);
  int lane = threadIdx.x & 63;
  float w[64];
  #pragma unroll
  for (int d = 0; d < 64; d++) w[d] = W[d * 64 + lane];
  float bias = b[lane];
  float ps = 0.f, pss = 0.f;
  for (int n = gw; n < N; n += nw) {
    int nsg = __builtin_amdgcn_readfirstlane(n);
    const float* arow = agg + (size_t)nsg * 64;  // SGPR base -> s_load
    float acc = bias;
    #pragma unroll
    for (int d = 0; d < 64; d++) acc += arow[d] * w[d];
    hc[(size_t)nsg * 64 + lane] = acc;
    ps += acc;
    pss += acc * acc;
  }
  atomicAdd(&stats[lane], ps);
  atomicAdd(&stats[64 + lane], pss);
}

// ---------------- fused BN finalize + apply + residual + pre-scale ----------------
__global__ __launch_bounds__(256, 8)
void apply_kernel(const float* __restrict__ hc, const float* __restrict__ stats,
                  const float* __restrict__ gamma, const float* __restrict__ beta,
                  const float* __restrict__ norm_src, float* __restrict__ h,
                  float* __restrict__ hs, int N) {
  __shared__ float s_scale[64];
  __shared__ float s_shift[64];
  int tid = threadIdx.x;
  if (tid < 64) {
    float s = stats[tid];
    float ss = stats[64 + tid];
    float invN = 1.0f / (float)N;
    float mean = s * invN;
    float var = fmaxf(ss * invN - mean * mean, 0.0f);
    float scale = gamma[tid] * rsqrtf(var + BN_EPS);
    s_scale[tid] = scale;
    s_shift[tid] = beta[tid] - mean * scale;
  }
  __syncthreads();
  int total4 = N * 16;
  int i = blockIdx.x * blockDim.x + threadIdx.x;
  int stride = gridDim.x * blockDim.x;
  for (; i < total4; i += stride) {
    float4 v = ((const float4*)hc)[i];
    float4 r = ((const float4*)h)[i];
    int cb = (i * 4) & 63;
    int n = i >> 4;
    float nsc = norm_src[n];
    float o0 = v.x * s_scale[cb + 0] + s_shift[cb + 0];
    float o1 = v.y * s_scale[cb + 1] + s_shift[cb + 1];
    float o2 = v.z * s_scale[cb + 2] + s_shift[cb + 2];
    float o3 = v.w * s_scale[cb + 3] + s_shift[cb + 3];
    o0 = (o0 >= 0.f) ? o0 : LEAKY_SLOPE * o0;
    o1 = (o1 >= 0.f) ? o1 : LEAKY_SLOPE * o1;
    o2 = (o2 >= 0.f) ? o2 : LEAKY_SLOPE * o2;
    o3 = (o3 >= 0.f) ? o3 : LEAKY_SLOPE * o3;
    float4 oh;
    oh.x = o0 + r.x; oh.y = o1 + r.y; oh.z = o2 + r.z; oh.w = o3 + r.w;
    ((float4*)h)[i] = oh;
    float4 os;
    os.x = oh.x * nsc; os.y = oh.y * nsc; os.z = oh.z * nsc; os.w = oh.w * nsc;
    ((float4*)hs)[i] = os;
  }
}

// ---------------- output: logits = h @ W_out + b_out; log_softmax ----------------
__global__ __launch_bounds__(256, 2)
void out_kernel(const float* __restrict__ h, const float* __restrict__ W_out,
                const float* __restrict__ b_out, float* __restrict__ out, int N) {
  int gw = (int)((blockIdx.x * blockDim.x + threadIdx.x) >> 6);
  int nw = (int)((gridDim.x * blockDim.x) >> 6);
  int lane = threadIdx.x & 63;
  float w[64];
  #pragma unroll
  for (int d = 0; d < 64; d++) w[d] = (lane < 40) ? W_out[d * 40 + lane] : 0.f;
  float bias = (lane < 40) ? b_out[lane] : 0.f;
  for (int n = gw; n < N; n += nw) {
    int nsg = __builtin_amdgcn_readfirstlane(n);
    const float* hrow = h + (size_t)nsg * 64;  // SGPR base -> s_load
    float acc = bias;
    #pragma unroll
    for (int d = 0; d < 64; d++) acc += hrow[d] * w[d];
    float lg = (lane < 40) ? acc : -INFINITY;
    float m = lg;
    #pragma unroll
    for (int off = 32; off; off >>= 1) m = fmaxf(m, __shfl_xor(m, off));
    float e = (lane < 40) ? expf(acc - m) : 0.f;
    float s = e;
    #pragma unroll
    for (int off = 32; off; off >>= 1) s += __shfl_xor(s, off);
    float lse = m + logf(s);
    if (lane < 40) out[(size_t)nsg * 40 + lane] = acc - lse;
  }
}

extern "C" void kernel_launch(void* const* d_in, const int* in_sizes, int n_in,
                              void* d_out, int out_size, void* d_ws, size_t ws_size,
                              hipStream_t stream) {
  const float* V     = (const float*)d_in[0];
  const int*   src   = (const int*)d_in[1];
  const int*   dst   = (const int*)d_in[2];
  const float* W_in  = (const float*)d_in[3];
  const float* b_in  = (const float*)d_in[4];
  const float* W_l   = (const float*)d_in[5];
  const float* b_l   = (const float*)d_in[6];
  const float* gamma = (const float*)d_in[7];
  const float* beta  = (const float*)d_in[8];
  const float* W_out = (const float*)d_in[9];
  const float* b_out = (const float*)d_in[10];
  float* out = (float*)d_out;

  const int N = in_sizes[0] / 128;  // 100000
  const int E = in_sizes[1];        // 1600000
  const int NL = 4;

  char* p = (char*)d_ws;
  auto alloc = [&](size_t bytes) {
    void* r = (void*)p;
    p += (bytes + 255) & ~(size_t)255;
    return r;
  };
  float* h       = (float*)alloc((size_t)N * 64 * 4);
  float* agg     = (float*)alloc((size_t)N * 64 * 4);
  float* hc      = (float*)alloc((size_t)N * 64 * 4);  // aliased: also hs
  int*   bucket  = (int*)alloc((size_t)E * 4);
  int*   cnt_src = (int*)alloc((size_t)N * 4);
  int*   cnt_dst = (int*)alloc((size_t)N * 4);
  int*   row_st  = (int*)alloc((size_t)N * 4);
  int*   cursor  = (int*)alloc((size_t)N * 4);
  float* nrm_src = (float*)alloc((size_t)N * 4);
  float* nrm_dst = (float*)alloc((size_t)N * 4);
  float* stats   = (float*)alloc(128 * 4);
  int*   g_cur   = (int*)alloc(256);
  (void)ws_size;
  float* hs = hc;  // alias: hs consumed by agg before gemm_stats rewrites hc

  hipMemsetAsync(cnt_src, 0, (size_t)N * 4, stream);
  hipMemsetAsync(cnt_dst, 0, (size_t)N * 4, stream);
  hipMemsetAsync(g_cur, 0, 4, stream);

  hist_kernel<<<2048, 256, 0, stream>>>(src, dst, cnt_src, cnt_dst, E);
  norm_offsets_kernel<<<(N + 255) / 256, 256, 0, stream>>>(cnt_src, cnt_dst, nrm_src, nrm_dst,
                                                           row_st, cursor, g_cur, N);
  fill_kernel<<<2048, 256, 0, stream>>>(src, dst, cursor, bucket, E);

  input_gemm_kernel<<<2048, 256, 0, stream>>>(V, W_in, b_in, nrm_src, h, hs, N);

  for (int l = 0; l < NL; l++) {
    agg_kernel<<<(N + 3) / 4, 256, 0, stream>>>(hs, nrm_dst, row_st, cnt_dst,
                                                bucket, agg, N);
    hipMemsetAsync(stats, 0, 128 * 4, stream);
    gemm_stats_kernel<<<2048, 256, 0, stream>>>(agg, W_l + (size_t)l * 64 * 64,
                                                b_l + (size_t)l * 64, hc, stats, N);
    apply_kernel<<<2048, 256, 0, stream>>>(hc, stats, gamma + (size_t)l * 64,
                                           beta + (size_t)l * 64, nrm_src, h, hs, N);
  }

  out_kernel<<<2048, 256, 0, stream>>>(h, W_out, b_out, out, N);
}